// Round 7
// baseline (938.112 us; speedup 1.0000x reference)
//
#include <hip/hip_runtime.h>

#define DIM 64
#define LN_EPS 1e-5f
#define XS_STRIDE 68

// ---------------- CSR build (once per call) ----------------

__global__ void k_zero(int* __restrict__ deg, int* __restrict__ counter, int n) {
    int i = blockIdx.x * blockDim.x + threadIdx.x;
    if (i < n) deg[i] = 0;
    if (i == 0) { counter[0] = 0; counter[1] = 0; }
}

__global__ void k_count(const int* __restrict__ dst, int* __restrict__ deg, int e_cnt) {
    int e = blockIdx.x * blockDim.x + threadIdx.x;
    if (e < e_cnt) atomicAdd(&deg[dst[e]], 1);
}

__global__ void k_reserve(const int* __restrict__ deg, int* __restrict__ rowstart,
                          int* __restrict__ cursor, float* __restrict__ dinv,
                          int* __restrict__ counter, int n) {
    int i = blockIdx.x * blockDim.x + threadIdx.x;
    if (i >= n) return;
    int d = deg[i];
    int s = atomicAdd(counter, d);
    rowstart[i] = s;
    cursor[i] = s;
    dinv[i] = rsqrtf((float)(d + 1));
}

__global__ void k_fill(const int* __restrict__ src, const int* __restrict__ dst,
                       const float* __restrict__ dinv, int* __restrict__ cursor,
                       int2* __restrict__ csr, int e_cnt) {
    int e = blockIdx.x * blockDim.x + threadIdx.x;
    if (e >= e_cnt) return;
    int s = src[e], d = dst[e];
    int pos = atomicAdd(&cursor[d], 1);
    float w = dinv[s] * dinv[d];
    csr[pos] = make_int2(s, __float_as_int(w));
}

// ---------------- fused per-layer kernel ----------------
// Block = 512 threads (8 waves) = 64 output rows -> 6256 waves total,
// ~24 waves/CU (vs 12 at 256 threads) to hide gather latency.
// __launch_bounds__(512, 8): pin VGPR <= 64 so 8 waves/SIMD actually fit.
// RACE NOTE: xin and out must NOT alias within one dispatch — the gather
// reads arbitrary rows of xin while this block writes its own rows of out.
// kernel_launch ping-pongs layer outputs (out / bufA) to guarantee this.
// Phase 1: stage W (16 KB) into LDS; aggregate 64 rows into the x-tile LDS
//          buffer. Wave handles 8 rows as 2 iterations of 4 row-slots
//          (rs = lane>>4); each 16-lane group owns one row (fq = lane&15,
//          float4 per lane). 4-edge unroll + next-batch csr prefetch
//          (software pipeline) to break the csr->gather serial chain.
// Phase 2: register-tile GEMM (2 rows x 4 cols per lane) + bias + LayerNorm
//          (shfl_xor over 16-lane groups) + ReLU, store float4.
__global__ __launch_bounds__(512, 8) void k_layer(const int* __restrict__ rowstart,
                                                  const int* __restrict__ deg,
                                                  const float* __restrict__ dinv,
                                                  const int2* __restrict__ csr,
                                                  const float* __restrict__ xin,
                                                  const float* __restrict__ W,
                                                  const float* __restrict__ b,
                                                  const float* __restrict__ gamma,
                                                  const float* __restrict__ beta,
                                                  float* __restrict__ out, int n) {
    __shared__ float ws[DIM * DIM];
    __shared__ float xs[64 * XS_STRIDE];
    int t = threadIdx.x;
    int base = blockIdx.x * 64;

    {   // stage W: 1024 float4 across 512 threads; issued first so the loads
        // overlap aggregation latency.
        const float4* W4 = (const float4*)W;
        float4* ws4 = (float4*)ws;
        ws4[t] = W4[t];
        ws4[t + 512] = W4[t + 512];
    }

    // ---- phase 1: aggregation into xs ----
    int wave = t >> 6, lane = t & 63;
    int rs = lane >> 4;    // row slot 0..3
    int fq = lane & 15;    // feature quad 0..15 (float4 each)
    const float4* xin4 = (const float4*)xin;

    for (int rr = 0; rr < 8; rr += 4) {
        int lrow = wave * 8 + rr + rs;    // local row 0..63
        int row = base + lrow;
        float4 acc = make_float4(0.f, 0.f, 0.f, 0.f);
        if (row < n) {
            int s0 = rowstart[row];
            int cnt = deg[row];
            int i = 0;
            int2 c0, c1, c2, c3;
            if (cnt >= 4) {
                c0 = csr[s0 + 0]; c1 = csr[s0 + 1];
                c2 = csr[s0 + 2]; c3 = csr[s0 + 3];
            }
            // software pipeline: prefetch batch i+4 while gathering batch i
            for (; i + 8 <= cnt; i += 4) {
                int2 n0 = csr[s0 + i + 4];
                int2 n1 = csr[s0 + i + 5];
                int2 n2 = csr[s0 + i + 6];
                int2 n3 = csr[s0 + i + 7];
                float4 h0 = xin4[(size_t)c0.x * 16 + fq];
                float4 h1 = xin4[(size_t)c1.x * 16 + fq];
                float4 h2 = xin4[(size_t)c2.x * 16 + fq];
                float4 h3 = xin4[(size_t)c3.x * 16 + fq];
                float w0 = __int_as_float(c0.y);
                float w1 = __int_as_float(c1.y);
                float w2 = __int_as_float(c2.y);
                float w3 = __int_as_float(c3.y);
                acc.x = fmaf(w0, h0.x, acc.x);
                acc.y = fmaf(w0, h0.y, acc.y);
                acc.z = fmaf(w0, h0.z, acc.z);
                acc.w = fmaf(w0, h0.w, acc.w);
                acc.x = fmaf(w1, h1.x, acc.x);
                acc.y = fmaf(w1, h1.y, acc.y);
                acc.z = fmaf(w1, h1.z, acc.z);
                acc.w = fmaf(w1, h1.w, acc.w);
                acc.x = fmaf(w2, h2.x, acc.x);
                acc.y = fmaf(w2, h2.y, acc.y);
                acc.z = fmaf(w2, h2.z, acc.z);
                acc.w = fmaf(w2, h2.w, acc.w);
                acc.x = fmaf(w3, h3.x, acc.x);
                acc.y = fmaf(w3, h3.y, acc.y);
                acc.z = fmaf(w3, h3.z, acc.z);
                acc.w = fmaf(w3, h3.w, acc.w);
                c0 = n0; c1 = n1; c2 = n2; c3 = n3;
            }
            if (i + 4 <= cnt) {   // drain the pipelined batch
                float4 h0 = xin4[(size_t)c0.x * 16 + fq];
                float4 h1 = xin4[(size_t)c1.x * 16 + fq];
                float4 h2 = xin4[(size_t)c2.x * 16 + fq];
                float4 h3 = xin4[(size_t)c3.x * 16 + fq];
                float w0 = __int_as_float(c0.y);
                float w1 = __int_as_float(c1.y);
                float w2 = __int_as_float(c2.y);
                float w3 = __int_as_float(c3.y);
                acc.x = fmaf(w0, h0.x, acc.x);
                acc.y = fmaf(w0, h0.y, acc.y);
                acc.z = fmaf(w0, h0.z, acc.z);
                acc.w = fmaf(w0, h0.w, acc.w);
                acc.x = fmaf(w1, h1.x, acc.x);
                acc.y = fmaf(w1, h1.y, acc.y);
                acc.z = fmaf(w1, h1.z, acc.z);
                acc.w = fmaf(w1, h1.w, acc.w);
                acc.x = fmaf(w2, h2.x, acc.x);
                acc.y = fmaf(w2, h2.y, acc.y);
                acc.z = fmaf(w2, h2.z, acc.z);
                acc.w = fmaf(w2, h2.w, acc.w);
                acc.x = fmaf(w3, h3.x, acc.x);
                acc.y = fmaf(w3, h3.y, acc.y);
                acc.z = fmaf(w3, h3.z, acc.z);
                acc.w = fmaf(w3, h3.w, acc.w);
                i += 4;
            }
            for (; i < cnt; i++) {
                int2 e0 = csr[s0 + i];
                float4 h0 = xin4[(size_t)e0.x * 16 + fq];
                float w0 = __int_as_float(e0.y);
                acc.x = fmaf(w0, h0.x, acc.x);
                acc.y = fmaf(w0, h0.y, acc.y);
                acc.z = fmaf(w0, h0.z, acc.z);
                acc.w = fmaf(w0, h0.w, acc.w);
            }
            // self-loop: dinv^2 * x[row]
            float di = dinv[row];
            float w = di * di;
            float4 xv = xin4[(size_t)row * 16 + fq];
            acc.x = fmaf(w, xv.x, acc.x);
            acc.y = fmaf(w, xv.y, acc.y);
            acc.z = fmaf(w, xv.z, acc.z);
            acc.w = fmaf(w, xv.w, acc.w);
        }
        *(float4*)(xs + lrow * XS_STRIDE + fq * 4) = acc;
    }
    __syncthreads();

    // ---- phase 2: GEMM + bias + LN + relu ----
    int rp = lane >> 4;                // row-pair index 0..3
    int c4 = lane & 15;                // col group (4 cols)
    int row0 = wave * 8 + rp * 2;      // local row base (2 rows)

    float4 acc[2];
    acc[0] = make_float4(0.f, 0.f, 0.f, 0.f);
    acc[1] = make_float4(0.f, 0.f, 0.f, 0.f);

    for (int kc = 0; kc < 16; kc++) {
        float4 w0 = *(const float4*)(ws + (4 * kc + 0) * DIM + c4 * 4);
        float4 w1 = *(const float4*)(ws + (4 * kc + 1) * DIM + c4 * 4);
        float4 w2 = *(const float4*)(ws + (4 * kc + 2) * DIM + c4 * 4);
        float4 w3 = *(const float4*)(ws + (4 * kc + 3) * DIM + c4 * 4);
#pragma unroll
        for (int j = 0; j < 2; j++) {
            float4 xv = *(const float4*)(xs + (row0 + j) * XS_STRIDE + kc * 4);
            acc[j].x = fmaf(xv.x, w0.x, acc[j].x);
            acc[j].y = fmaf(xv.x, w0.y, acc[j].y);
            acc[j].z = fmaf(xv.x, w0.z, acc[j].z);
            acc[j].w = fmaf(xv.x, w0.w, acc[j].w);
            acc[j].x = fmaf(xv.y, w1.x, acc[j].x);
            acc[j].y = fmaf(xv.y, w1.y, acc[j].y);
            acc[j].z = fmaf(xv.y, w1.z, acc[j].z);
            acc[j].w = fmaf(xv.y, w1.w, acc[j].w);
            acc[j].x = fmaf(xv.z, w2.x, acc[j].x);
            acc[j].y = fmaf(xv.z, w2.y, acc[j].y);
            acc[j].z = fmaf(xv.z, w2.z, acc[j].z);
            acc[j].w = fmaf(xv.z, w2.w, acc[j].w);
            acc[j].x = fmaf(xv.w, w3.x, acc[j].x);
            acc[j].y = fmaf(xv.w, w3.y, acc[j].y);
            acc[j].z = fmaf(xv.w, w3.z, acc[j].z);
            acc[j].w = fmaf(xv.w, w3.w, acc[j].w);
        }
    }

    float4 b4 = *(const float4*)(b + c4 * 4);
    float4 g4 = *(const float4*)(gamma + c4 * 4);
    float4 be4 = *(const float4*)(beta + c4 * 4);
#pragma unroll
    for (int j = 0; j < 2; j++) {
        float4 v = make_float4(acc[j].x + b4.x, acc[j].y + b4.y,
                               acc[j].z + b4.z, acc[j].w + b4.w);
        float s = v.x + v.y + v.z + v.w;
        s += __shfl_xor(s, 1, 64);
        s += __shfl_xor(s, 2, 64);
        s += __shfl_xor(s, 4, 64);
        s += __shfl_xor(s, 8, 64);
        float mu = s * (1.0f / 64.0f);
        float4 d = make_float4(v.x - mu, v.y - mu, v.z - mu, v.w - mu);
        float q = d.x * d.x + d.y * d.y + d.z * d.z + d.w * d.w;
        q += __shfl_xor(q, 1, 64);
        q += __shfl_xor(q, 2, 64);
        q += __shfl_xor(q, 4, 64);
        q += __shfl_xor(q, 8, 64);
        float rstd = rsqrtf(q * (1.0f / 64.0f) + LN_EPS);
        float4 y = make_float4(fmaxf(fmaf(d.x * rstd, g4.x, be4.x), 0.f),
                               fmaxf(fmaf(d.y * rstd, g4.y, be4.y), 0.f),
                               fmaxf(fmaf(d.z * rstd, g4.z, be4.z), 0.f),
                               fmaxf(fmaf(d.w * rstd, g4.w, be4.w), 0.f));
        int grow = base + row0 + j;
        if (grow < n)
            *(float4*)(out + (size_t)grow * DIM + c4 * 4) = y;
    }
}

// ---------------- launch ----------------

extern "C" void kernel_launch(void* const* d_in, const int* in_sizes, int n_in,
                              void* d_out, int out_size, void* d_ws, size_t ws_size,
                              hipStream_t stream) {
    const float* x      = (const float*)d_in[0];
    const int*   ei     = (const int*)  d_in[1];
    const float* Ws     = (const float*)d_in[2];
    const float* bs     = (const float*)d_in[3];
    const float* gammas = (const float*)d_in[4];
    const float* betas  = (const float*)d_in[5];
    float* out = (float*)d_out;

    int n = in_sizes[0] / DIM;
    int E = in_sizes[1] / 2;
    int n_layers = in_sizes[2] / (DIM * DIM);

    const int* srcp = ei;
    const int* dstp = ei + E;

    // ws: deg[n] | rowstart[n] | cursor[n] | dinv[n] | counter[2] | csr[E] int2 | bufA[n*64]
    int* deg      = (int*)d_ws;
    int* rowstart = deg + n;
    int* cursor   = rowstart + n;
    float* dinv   = (float*)(cursor + n);
    int* counter  = (int*)(dinv + n);
    int2* csr     = (int2*)(counter + 2);
    float* bufA   = (float*)(csr + E);

    int nb_n = (n + 255) / 256;
    int nb_e = (E + 255) / 256;

    k_zero   <<<nb_n, 256, 0, stream>>>(deg, counter, n);
    k_count  <<<nb_e, 256, 0, stream>>>(dstp, deg, E);
    k_reserve<<<nb_n, 256, 0, stream>>>(deg, rowstart, cursor, dinv, counter, n);
    k_fill   <<<nb_e, 256, 0, stream>>>(srcp, dstp, dinv, cursor, csr, E);

    // Ping-pong layer outputs so xin never aliases the write target within
    // a dispatch (the gather reads arbitrary rows). Final layer lands in out.
    int nb_tile = (n + 63) / 64;
    const float* src_buf = x;
    for (int i = 0; i < n_layers; i++) {
        float* dst = (((n_layers - 1 - i) & 1) == 0) ? out : bufA;
        k_layer<<<nb_tile, 512, 0, stream>>>(rowstart, deg, dinv, csr, src_buf,
                                             Ws + (size_t)i * DIM * DIM,
                                             bs + (size_t)i * DIM,
                                             gammas + (size_t)i * DIM,
                                             betas + (size_t)i * DIM, dst, n);
        src_buf = dst;
    }
}

// Round 8
// 776.618 us; speedup vs baseline: 1.2079x; 1.2079x over previous
//
#include <hip/hip_runtime.h>

#define DIM 64
#define LN_EPS 1e-5f
#define XS_STRIDE 68

// ---------------- CSR build (once per call) ----------------

__global__ void k_zero(int* __restrict__ deg, int* __restrict__ counter, int n) {
    int i = blockIdx.x * blockDim.x + threadIdx.x;
    if (i < n) deg[i] = 0;
    if (i == 0) { counter[0] = 0; counter[1] = 0; }
}

__global__ void k_count(const int* __restrict__ dst, int* __restrict__ deg, int e_cnt) {
    int e = blockIdx.x * blockDim.x + threadIdx.x;
    if (e < e_cnt) atomicAdd(&deg[dst[e]], 1);
}

__global__ void k_reserve(const int* __restrict__ deg, int* __restrict__ rowstart,
                          int* __restrict__ cursor, float* __restrict__ dinv,
                          int* __restrict__ counter, int n) {
    int i = blockIdx.x * blockDim.x + threadIdx.x;
    if (i >= n) return;
    int d = deg[i];
    int s = atomicAdd(counter, d);
    rowstart[i] = s;
    cursor[i] = s;
    dinv[i] = rsqrtf((float)(d + 1));
}

__global__ void k_fill(const int* __restrict__ src, const int* __restrict__ dst,
                       const float* __restrict__ dinv, int* __restrict__ cursor,
                       int2* __restrict__ csr, int e_cnt) {
    int e = blockIdx.x * blockDim.x + threadIdx.x;
    if (e >= e_cnt) return;
    int s = src[e], d = dst[e];
    int pos = atomicAdd(&cursor[d], 1);
    float w = dinv[s] * dinv[d];
    csr[pos] = make_int2(s, __float_as_int(w));
}

// ---------------- fused per-layer kernel ----------------
// Block = 512 threads (8 waves) = 64 output rows.
// VGPR NOTE (round-7 lesson): __launch_bounds__(512, 8) pinned VGPR to 32 on
// this toolchain -> ~700 MB/dispatch scratch spills, 5.7x regression. The
// kernel needs ~52 live VGPRs. Use (512, 4): cap 128, compiler lands ~52-64
// spill-free; occupancy then reaches 8 waves/SIMD via LDS (4 blocks/CU) and
// natural VGPR <= 64 allocation.
// RACE NOTE: xin and out must NOT alias within one dispatch — the gather
// reads arbitrary rows of xin while this block writes its own rows of out.
// kernel_launch ping-pongs layer outputs (out / bufA) to guarantee this.
// Phase 1: stage W (16 KB) into LDS; aggregate 64 rows into the x-tile LDS
//          buffer. Wave handles 8 rows as 2 iterations of 4 row-slots
//          (rs = lane>>4); each 16-lane group owns one row (fq = lane&15,
//          float4 per lane). 4-edge unroll + next-batch csr prefetch
//          (software pipeline) to break the csr->gather serial chain.
// Phase 2: register-tile GEMM (2 rows x 4 cols per lane) + bias + LayerNorm
//          (shfl_xor over 16-lane groups) + ReLU, store float4.
__global__ __launch_bounds__(512, 4) void k_layer(const int* __restrict__ rowstart,
                                                  const int* __restrict__ deg,
                                                  const float* __restrict__ dinv,
                                                  const int2* __restrict__ csr,
                                                  const float* __restrict__ xin,
                                                  const float* __restrict__ W,
                                                  const float* __restrict__ b,
                                                  const float* __restrict__ gamma,
                                                  const float* __restrict__ beta,
                                                  float* __restrict__ out, int n) {
    __shared__ float ws[DIM * DIM];
    __shared__ float xs[64 * XS_STRIDE];
    int t = threadIdx.x;
    int base = blockIdx.x * 64;

    {   // stage W: 1024 float4 across 512 threads; issued first so the loads
        // overlap aggregation latency.
        const float4* W4 = (const float4*)W;
        float4* ws4 = (float4*)ws;
        ws4[t] = W4[t];
        ws4[t + 512] = W4[t + 512];
    }

    // ---- phase 1: aggregation into xs ----
    int wave = t >> 6, lane = t & 63;
    int rs = lane >> 4;    // row slot 0..3
    int fq = lane & 15;    // feature quad 0..15 (float4 each)
    const float4* xin4 = (const float4*)xin;

    for (int rr = 0; rr < 8; rr += 4) {
        int lrow = wave * 8 + rr + rs;    // local row 0..63
        int row = base + lrow;
        float4 acc = make_float4(0.f, 0.f, 0.f, 0.f);
        if (row < n) {
            int s0 = rowstart[row];
            int cnt = deg[row];
            int i = 0;
            int2 c0, c1, c2, c3;
            if (cnt >= 4) {
                c0 = csr[s0 + 0]; c1 = csr[s0 + 1];
                c2 = csr[s0 + 2]; c3 = csr[s0 + 3];
            }
            // software pipeline: prefetch batch i+4 while gathering batch i
            for (; i + 8 <= cnt; i += 4) {
                int2 n0 = csr[s0 + i + 4];
                int2 n1 = csr[s0 + i + 5];
                int2 n2 = csr[s0 + i + 6];
                int2 n3 = csr[s0 + i + 7];
                float4 h0 = xin4[(size_t)c0.x * 16 + fq];
                float4 h1 = xin4[(size_t)c1.x * 16 + fq];
                float4 h2 = xin4[(size_t)c2.x * 16 + fq];
                float4 h3 = xin4[(size_t)c3.x * 16 + fq];
                float w0 = __int_as_float(c0.y);
                float w1 = __int_as_float(c1.y);
                float w2 = __int_as_float(c2.y);
                float w3 = __int_as_float(c3.y);
                acc.x = fmaf(w0, h0.x, acc.x);
                acc.y = fmaf(w0, h0.y, acc.y);
                acc.z = fmaf(w0, h0.z, acc.z);
                acc.w = fmaf(w0, h0.w, acc.w);
                acc.x = fmaf(w1, h1.x, acc.x);
                acc.y = fmaf(w1, h1.y, acc.y);
                acc.z = fmaf(w1, h1.z, acc.z);
                acc.w = fmaf(w1, h1.w, acc.w);
                acc.x = fmaf(w2, h2.x, acc.x);
                acc.y = fmaf(w2, h2.y, acc.y);
                acc.z = fmaf(w2, h2.z, acc.z);
                acc.w = fmaf(w2, h2.w, acc.w);
                acc.x = fmaf(w3, h3.x, acc.x);
                acc.y = fmaf(w3, h3.y, acc.y);
                acc.z = fmaf(w3, h3.z, acc.z);
                acc.w = fmaf(w3, h3.w, acc.w);
                c0 = n0; c1 = n1; c2 = n2; c3 = n3;
            }
            if (i + 4 <= cnt) {   // drain the pipelined batch
                float4 h0 = xin4[(size_t)c0.x * 16 + fq];
                float4 h1 = xin4[(size_t)c1.x * 16 + fq];
                float4 h2 = xin4[(size_t)c2.x * 16 + fq];
                float4 h3 = xin4[(size_t)c3.x * 16 + fq];
                float w0 = __int_as_float(c0.y);
                float w1 = __int_as_float(c1.y);
                float w2 = __int_as_float(c2.y);
                float w3 = __int_as_float(c3.y);
                acc.x = fmaf(w0, h0.x, acc.x);
                acc.y = fmaf(w0, h0.y, acc.y);
                acc.z = fmaf(w0, h0.z, acc.z);
                acc.w = fmaf(w0, h0.w, acc.w);
                acc.x = fmaf(w1, h1.x, acc.x);
                acc.y = fmaf(w1, h1.y, acc.y);
                acc.z = fmaf(w1, h1.z, acc.z);
                acc.w = fmaf(w1, h1.w, acc.w);
                acc.x = fmaf(w2, h2.x, acc.x);
                acc.y = fmaf(w2, h2.y, acc.y);
                acc.z = fmaf(w2, h2.z, acc.z);
                acc.w = fmaf(w2, h2.w, acc.w);
                acc.x = fmaf(w3, h3.x, acc.x);
                acc.y = fmaf(w3, h3.y, acc.y);
                acc.z = fmaf(w3, h3.z, acc.z);
                acc.w = fmaf(w3, h3.w, acc.w);
                i += 4;
            }
            for (; i < cnt; i++) {
                int2 e0 = csr[s0 + i];
                float4 h0 = xin4[(size_t)e0.x * 16 + fq];
                float w0 = __int_as_float(e0.y);
                acc.x = fmaf(w0, h0.x, acc.x);
                acc.y = fmaf(w0, h0.y, acc.y);
                acc.z = fmaf(w0, h0.z, acc.z);
                acc.w = fmaf(w0, h0.w, acc.w);
            }
            // self-loop: dinv^2 * x[row]
            float di = dinv[row];
            float w = di * di;
            float4 xv = xin4[(size_t)row * 16 + fq];
            acc.x = fmaf(w, xv.x, acc.x);
            acc.y = fmaf(w, xv.y, acc.y);
            acc.z = fmaf(w, xv.z, acc.z);
            acc.w = fmaf(w, xv.w, acc.w);
        }
        *(float4*)(xs + lrow * XS_STRIDE + fq * 4) = acc;
    }
    __syncthreads();

    // ---- phase 2: GEMM + bias + LN + relu ----
    int rp = lane >> 4;                // row-pair index 0..3
    int c4 = lane & 15;                // col group (4 cols)
    int row0 = wave * 8 + rp * 2;      // local row base (2 rows)

    float4 acc[2];
    acc[0] = make_float4(0.f, 0.f, 0.f, 0.f);
    acc[1] = make_float4(0.f, 0.f, 0.f, 0.f);

    for (int kc = 0; kc < 16; kc++) {
        float4 w0 = *(const float4*)(ws + (4 * kc + 0) * DIM + c4 * 4);
        float4 w1 = *(const float4*)(ws + (4 * kc + 1) * DIM + c4 * 4);
        float4 w2 = *(const float4*)(ws + (4 * kc + 2) * DIM + c4 * 4);
        float4 w3 = *(const float4*)(ws + (4 * kc + 3) * DIM + c4 * 4);
#pragma unroll
        for (int j = 0; j < 2; j++) {
            float4 xv = *(const float4*)(xs + (row0 + j) * XS_STRIDE + kc * 4);
            acc[j].x = fmaf(xv.x, w0.x, acc[j].x);
            acc[j].y = fmaf(xv.x, w0.y, acc[j].y);
            acc[j].z = fmaf(xv.x, w0.z, acc[j].z);
            acc[j].w = fmaf(xv.x, w0.w, acc[j].w);
            acc[j].x = fmaf(xv.y, w1.x, acc[j].x);
            acc[j].y = fmaf(xv.y, w1.y, acc[j].y);
            acc[j].z = fmaf(xv.y, w1.z, acc[j].z);
            acc[j].w = fmaf(xv.y, w1.w, acc[j].w);
            acc[j].x = fmaf(xv.z, w2.x, acc[j].x);
            acc[j].y = fmaf(xv.z, w2.y, acc[j].y);
            acc[j].z = fmaf(xv.z, w2.z, acc[j].z);
            acc[j].w = fmaf(xv.z, w2.w, acc[j].w);
            acc[j].x = fmaf(xv.w, w3.x, acc[j].x);
            acc[j].y = fmaf(xv.w, w3.y, acc[j].y);
            acc[j].z = fmaf(xv.w, w3.z, acc[j].z);
            acc[j].w = fmaf(xv.w, w3.w, acc[j].w);
        }
    }

    float4 b4 = *(const float4*)(b + c4 * 4);
    float4 g4 = *(const float4*)(gamma + c4 * 4);
    float4 be4 = *(const float4*)(beta + c4 * 4);
#pragma unroll
    for (int j = 0; j < 2; j++) {
        float4 v = make_float4(acc[j].x + b4.x, acc[j].y + b4.y,
                               acc[j].z + b4.z, acc[j].w + b4.w);
        float s = v.x + v.y + v.z + v.w;
        s += __shfl_xor(s, 1, 64);
        s += __shfl_xor(s, 2, 64);
        s += __shfl_xor(s, 4, 64);
        s += __shfl_xor(s, 8, 64);
        float mu = s * (1.0f / 64.0f);
        float4 d = make_float4(v.x - mu, v.y - mu, v.z - mu, v.w - mu);
        float q = d.x * d.x + d.y * d.y + d.z * d.z + d.w * d.w;
        q += __shfl_xor(q, 1, 64);
        q += __shfl_xor(q, 2, 64);
        q += __shfl_xor(q, 4, 64);
        q += __shfl_xor(q, 8, 64);
        float rstd = rsqrtf(q * (1.0f / 64.0f) + LN_EPS);
        float4 y = make_float4(fmaxf(fmaf(d.x * rstd, g4.x, be4.x), 0.f),
                               fmaxf(fmaf(d.y * rstd, g4.y, be4.y), 0.f),
                               fmaxf(fmaf(d.z * rstd, g4.z, be4.z), 0.f),
                               fmaxf(fmaf(d.w * rstd, g4.w, be4.w), 0.f));
        int grow = base + row0 + j;
        if (grow < n)
            *(float4*)(out + (size_t)grow * DIM + c4 * 4) = y;
    }
}

// ---------------- launch ----------------

extern "C" void kernel_launch(void* const* d_in, const int* in_sizes, int n_in,
                              void* d_out, int out_size, void* d_ws, size_t ws_size,
                              hipStream_t stream) {
    const float* x      = (const float*)d_in[0];
    const int*   ei     = (const int*)  d_in[1];
    const float* Ws     = (const float*)d_in[2];
    const float* bs     = (const float*)d_in[3];
    const float* gammas = (const float*)d_in[4];
    const float* betas  = (const float*)d_in[5];
    float* out = (float*)d_out;

    int n = in_sizes[0] / DIM;
    int E = in_sizes[1] / 2;
    int n_layers = in_sizes[2] / (DIM * DIM);

    const int* srcp = ei;
    const int* dstp = ei + E;

    // ws: deg[n] | rowstart[n] | cursor[n] | dinv[n] | counter[2] | csr[E] int2 | bufA[n*64]
    int* deg      = (int*)d_ws;
    int* rowstart = deg + n;
    int* cursor   = rowstart + n;
    float* dinv   = (float*)(cursor + n);
    int* counter  = (int*)(dinv + n);
    int2* csr     = (int2*)(counter + 2);
    float* bufA   = (float*)(csr + E);

    int nb_n = (n + 255) / 256;
    int nb_e = (E + 255) / 256;

    k_zero   <<<nb_n, 256, 0, stream>>>(deg, counter, n);
    k_count  <<<nb_e, 256, 0, stream>>>(dstp, deg, E);
    k_reserve<<<nb_n, 256, 0, stream>>>(deg, rowstart, cursor, dinv, counter, n);
    k_fill   <<<nb_e, 256, 0, stream>>>(srcp, dstp, dinv, cursor, csr, E);

    // Ping-pong layer outputs so xin never aliases the write target within
    // a dispatch (the gather reads arbitrary rows). Final layer lands in out.
    int nb_tile = (n + 63) / 64;
    const float* src_buf = x;
    for (int i = 0; i < n_layers; i++) {
        float* dst = (((n_layers - 1 - i) & 1) == 0) ? out : bufA;
        k_layer<<<nb_tile, 512, 0, stream>>>(rowstart, deg, dinv, csr, src_buf,
                                             Ws + (size_t)i * DIM * DIM,
                                             bs + (size_t)i * DIM,
                                             gammas + (size_t)i * DIM,
                                             betas + (size_t)i * DIM, dst, n);
        src_buf = dst;
    }
}

// Round 9
// 275.710 us; speedup vs baseline: 3.4025x; 2.8168x over previous
//
#include <hip/hip_runtime.h>

#define DIM 64
#define LN_EPS 1e-5f
#define XS_STRIDE 68
#define RPB 16   // rows per block

// ---------------- CSR build (once per call) ----------------

__global__ void k_zero(int* __restrict__ deg, int* __restrict__ counter, int n) {
    int i = blockIdx.x * blockDim.x + threadIdx.x;
    if (i < n) deg[i] = 0;
    if (i == 0) { counter[0] = 0; counter[1] = 0; }
}

__global__ void k_count(const int* __restrict__ dst, int* __restrict__ deg, int e_cnt) {
    int e = blockIdx.x * blockDim.x + threadIdx.x;
    if (e < e_cnt) atomicAdd(&deg[dst[e]], 1);
}

__global__ void k_reserve(const int* __restrict__ deg, int* __restrict__ rowstart,
                          int* __restrict__ cursor, float* __restrict__ dinv,
                          int* __restrict__ counter, int n) {
    int i = blockIdx.x * blockDim.x + threadIdx.x;
    if (i >= n) return;
    int d = deg[i];
    int s = atomicAdd(counter, d);
    rowstart[i] = s;
    cursor[i] = s;
    dinv[i] = rsqrtf((float)(d + 1));
}

__global__ void k_fill(const int* __restrict__ src, const int* __restrict__ dst,
                       const float* __restrict__ dinv, int* __restrict__ cursor,
                       int2* __restrict__ csr, int e_cnt) {
    int e = blockIdx.x * blockDim.x + threadIdx.x;
    if (e >= e_cnt) return;
    int s = src[e], d = dst[e];
    int pos = atomicAdd(&cursor[d], 1);
    float w = dinv[s] * dinv[d];
    csr[pos] = make_int2(s, __float_as_int(w));
}

// ---------------- fused per-layer kernel ----------------
// Block = 256 threads (4 waves) = 16 output rows -> 3125 blocks, ~28 waves/CU
// (LDS-limited: 20.6 KB/block -> 7 blocks/CU). Occupancy comes from MORE
// BLOCKS, not fatter blocks.
// SPILL NOTE (rounds 7-8 lesson): 512-thread variants with csr prefetch
// spilled (~370-470 MB/dispatch scratch writes) at both launch_bounds (512,8)
// and (512,4). This kernel is a strict simplification of the round-4
// spill-free structure (VGPR 52): one row per 16-lane group, no prefetch
// pipeline, phase-2 tile = 1 row x 4 cols per lane.
// RACE NOTE: xin and out must NOT alias within one dispatch — the gather
// reads arbitrary rows of xin while this block writes its own rows of out.
// kernel_launch ping-pongs layer outputs (out / bufA) to guarantee this.
__global__ __launch_bounds__(256) void k_layer(const int* __restrict__ rowstart,
                                               const int* __restrict__ deg,
                                               const float* __restrict__ dinv,
                                               const int2* __restrict__ csr,
                                               const float* __restrict__ xin,
                                               const float* __restrict__ W,
                                               const float* __restrict__ b,
                                               const float* __restrict__ gamma,
                                               const float* __restrict__ beta,
                                               float* __restrict__ out, int n) {
    __shared__ float ws[DIM * DIM];
    __shared__ float xs[RPB * XS_STRIDE];
    int t = threadIdx.x;
    int base = blockIdx.x * RPB;

    {   // stage W: 1024 float4 across 256 threads; issued first so the loads
        // overlap aggregation latency.
        const float4* W4 = (const float4*)W;
        float4* ws4 = (float4*)ws;
#pragma unroll
        for (int i = 0; i < 4; i++) ws4[t + 256 * i] = W4[t + 256 * i];
    }

    // ---- phase 1: aggregation into xs ----
    int wave = t >> 6, lane = t & 63;
    int rs = lane >> 4;    // row slot 0..3
    int fq = lane & 15;    // feature quad 0..15 (float4 each)
    int lrow = wave * 4 + rs;          // local row 0..15
    int row = base + lrow;
    const float4* xin4 = (const float4*)xin;

    float4 acc = make_float4(0.f, 0.f, 0.f, 0.f);
    if (row < n) {
        int s0 = rowstart[row];
        int cnt = deg[row];
        int i = 0;
        for (; i + 4 <= cnt; i += 4) {
            int2 e0 = csr[s0 + i + 0];
            int2 e1 = csr[s0 + i + 1];
            int2 e2 = csr[s0 + i + 2];
            int2 e3 = csr[s0 + i + 3];
            float4 h0 = xin4[(size_t)e0.x * 16 + fq];
            float4 h1 = xin4[(size_t)e1.x * 16 + fq];
            float4 h2 = xin4[(size_t)e2.x * 16 + fq];
            float4 h3 = xin4[(size_t)e3.x * 16 + fq];
            float w0 = __int_as_float(e0.y);
            float w1 = __int_as_float(e1.y);
            float w2 = __int_as_float(e2.y);
            float w3 = __int_as_float(e3.y);
            acc.x = fmaf(w0, h0.x, acc.x);
            acc.y = fmaf(w0, h0.y, acc.y);
            acc.z = fmaf(w0, h0.z, acc.z);
            acc.w = fmaf(w0, h0.w, acc.w);
            acc.x = fmaf(w1, h1.x, acc.x);
            acc.y = fmaf(w1, h1.y, acc.y);
            acc.z = fmaf(w1, h1.z, acc.z);
            acc.w = fmaf(w1, h1.w, acc.w);
            acc.x = fmaf(w2, h2.x, acc.x);
            acc.y = fmaf(w2, h2.y, acc.y);
            acc.z = fmaf(w2, h2.z, acc.z);
            acc.w = fmaf(w2, h2.w, acc.w);
            acc.x = fmaf(w3, h3.x, acc.x);
            acc.y = fmaf(w3, h3.y, acc.y);
            acc.z = fmaf(w3, h3.z, acc.z);
            acc.w = fmaf(w3, h3.w, acc.w);
        }
        for (; i < cnt; i++) {
            int2 e0 = csr[s0 + i];
            float4 h0 = xin4[(size_t)e0.x * 16 + fq];
            float w0 = __int_as_float(e0.y);
            acc.x = fmaf(w0, h0.x, acc.x);
            acc.y = fmaf(w0, h0.y, acc.y);
            acc.z = fmaf(w0, h0.z, acc.z);
            acc.w = fmaf(w0, h0.w, acc.w);
        }
        // self-loop: dinv^2 * x[row]
        float di = dinv[row];
        float w = di * di;
        float4 xv = xin4[(size_t)row * 16 + fq];
        acc.x = fmaf(w, xv.x, acc.x);
        acc.y = fmaf(w, xv.y, acc.y);
        acc.z = fmaf(w, xv.z, acc.z);
        acc.w = fmaf(w, xv.w, acc.w);
    }
    *(float4*)(xs + lrow * XS_STRIDE + fq * 4) = acc;
    __syncthreads();

    // ---- phase 2: GEMM + bias + LN + relu ----
    // Each lane: out[row][fq*4 .. fq*4+3] = sum_k xs[lrow][k] * W[k][fq*4..].
    // xs reads are group-broadcast (free); ws reads are float4-coalesced.
    float4 a2 = make_float4(0.f, 0.f, 0.f, 0.f);
    for (int kc = 0; kc < 16; kc++) {
        float4 xv = *(const float4*)(xs + lrow * XS_STRIDE + kc * 4);
        float4 w0 = *(const float4*)(ws + (4 * kc + 0) * DIM + fq * 4);
        float4 w1 = *(const float4*)(ws + (4 * kc + 1) * DIM + fq * 4);
        float4 w2 = *(const float4*)(ws + (4 * kc + 2) * DIM + fq * 4);
        float4 w3 = *(const float4*)(ws + (4 * kc + 3) * DIM + fq * 4);
        a2.x = fmaf(xv.x, w0.x, a2.x);
        a2.y = fmaf(xv.x, w0.y, a2.y);
        a2.z = fmaf(xv.x, w0.z, a2.z);
        a2.w = fmaf(xv.x, w0.w, a2.w);
        a2.x = fmaf(xv.y, w1.x, a2.x);
        a2.y = fmaf(xv.y, w1.y, a2.y);
        a2.z = fmaf(xv.y, w1.z, a2.z);
        a2.w = fmaf(xv.y, w1.w, a2.w);
        a2.x = fmaf(xv.z, w2.x, a2.x);
        a2.y = fmaf(xv.z, w2.y, a2.y);
        a2.z = fmaf(xv.z, w2.z, a2.z);
        a2.w = fmaf(xv.z, w2.w, a2.w);
        a2.x = fmaf(xv.w, w3.x, a2.x);
        a2.y = fmaf(xv.w, w3.y, a2.y);
        a2.z = fmaf(xv.w, w3.z, a2.z);
        a2.w = fmaf(xv.w, w3.w, a2.w);
    }

    float4 b4 = *(const float4*)(b + fq * 4);
    float4 g4 = *(const float4*)(gamma + fq * 4);
    float4 be4 = *(const float4*)(beta + fq * 4);

    float4 v = make_float4(a2.x + b4.x, a2.y + b4.y, a2.z + b4.z, a2.w + b4.w);
    float s = v.x + v.y + v.z + v.w;
    s += __shfl_xor(s, 1, 64);
    s += __shfl_xor(s, 2, 64);
    s += __shfl_xor(s, 4, 64);
    s += __shfl_xor(s, 8, 64);
    float mu = s * (1.0f / 64.0f);
    float4 d = make_float4(v.x - mu, v.y - mu, v.z - mu, v.w - mu);
    float q = d.x * d.x + d.y * d.y + d.z * d.z + d.w * d.w;
    q += __shfl_xor(q, 1, 64);
    q += __shfl_xor(q, 2, 64);
    q += __shfl_xor(q, 4, 64);
    q += __shfl_xor(q, 8, 64);
    float rstd = rsqrtf(q * (1.0f / 64.0f) + LN_EPS);
    float4 y = make_float4(fmaxf(fmaf(d.x * rstd, g4.x, be4.x), 0.f),
                           fmaxf(fmaf(d.y * rstd, g4.y, be4.y), 0.f),
                           fmaxf(fmaf(d.z * rstd, g4.z, be4.z), 0.f),
                           fmaxf(fmaf(d.w * rstd, g4.w, be4.w), 0.f));
    if (row < n)
        *(float4*)(out + (size_t)row * DIM + fq * 4) = y;
}

// ---------------- launch ----------------

extern "C" void kernel_launch(void* const* d_in, const int* in_sizes, int n_in,
                              void* d_out, int out_size, void* d_ws, size_t ws_size,
                              hipStream_t stream) {
    const float* x      = (const float*)d_in[0];
    const int*   ei     = (const int*)  d_in[1];
    const float* Ws     = (const float*)d_in[2];
    const float* bs     = (const float*)d_in[3];
    const float* gammas = (const float*)d_in[4];
    const float* betas  = (const float*)d_in[5];
    float* out = (float*)d_out;

    int n = in_sizes[0] / DIM;
    int E = in_sizes[1] / 2;
    int n_layers = in_sizes[2] / (DIM * DIM);

    const int* srcp = ei;
    const int* dstp = ei + E;

    // ws: deg[n] | rowstart[n] | cursor[n] | dinv[n] | counter[2] | csr[E] int2 | bufA[n*64]
    int* deg      = (int*)d_ws;
    int* rowstart = deg + n;
    int* cursor   = rowstart + n;
    float* dinv   = (float*)(cursor + n);
    int* counter  = (int*)(dinv + n);
    int2* csr     = (int2*)(counter + 2);
    float* bufA   = (float*)(csr + E);

    int nb_n = (n + 255) / 256;
    int nb_e = (E + 255) / 256;

    k_zero   <<<nb_n, 256, 0, stream>>>(deg, counter, n);
    k_count  <<<nb_e, 256, 0, stream>>>(dstp, deg, E);
    k_reserve<<<nb_n, 256, 0, stream>>>(deg, rowstart, cursor, dinv, counter, n);
    k_fill   <<<nb_e, 256, 0, stream>>>(srcp, dstp, dinv, cursor, csr, E);

    // Ping-pong layer outputs so xin never aliases the write target within
    // a dispatch (the gather reads arbitrary rows). Final layer lands in out.
    int nb_tile = (n + RPB - 1) / RPB;
    const float* src_buf = x;
    for (int i = 0; i < n_layers; i++) {
        float* dst = (((n_layers - 1 - i) & 1) == 0) ? out : bufA;
        k_layer<<<nb_tile, 256, 0, stream>>>(rowstart, deg, dinv, csr, src_buf,
                                             Ws + (size_t)i * DIM * DIM,
                                             bs + (size_t)i * DIM,
                                             gammas + (size_t)i * DIM,
                                             betas + (size_t)i * DIM, dst, n);
        src_buf = dst;
    }
}

// Round 10
// 252.481 us; speedup vs baseline: 3.7156x; 1.0920x over previous
//
#include <hip/hip_runtime.h>

#define DIM 64
#define LN_EPS 1e-5f
#define XS_STRIDE 68
#define RPB 16   // rows per block

// ---------------- CSR build (once per call) ----------------

__global__ void k_zero(int* __restrict__ deg, int* __restrict__ counter, int n) {
    int i = blockIdx.x * blockDim.x + threadIdx.x;
    if (i < n) deg[i] = 0;
    if (i == 0) { counter[0] = 0; counter[1] = 0; }
}

// rank trick: the degree-count atomic ALREADY returns each edge's unique
// slot within its destination row. Save it; k_fill then needs no atomics.
__global__ void k_count(const int* __restrict__ dst, int* __restrict__ deg,
                        int* __restrict__ rank, int e_cnt) {
    int e = blockIdx.x * blockDim.x + threadIdx.x;
    if (e < e_cnt) rank[e] = atomicAdd(&deg[dst[e]], 1);
}

__global__ void k_reserve(const int* __restrict__ deg, int* __restrict__ rowstart,
                          float* __restrict__ dinv,
                          int* __restrict__ counter, int n) {
    int i = blockIdx.x * blockDim.x + threadIdx.x;
    if (i >= n) return;
    int d = deg[i];
    int s = atomicAdd(counter, d);
    rowstart[i] = s;
    dinv[i] = rsqrtf((float)(d + 1));
}

// atomic-free scatter: pos = rowstart[dst] + rank (unique, in-range)
__global__ void k_fill(const int* __restrict__ src, const int* __restrict__ dst,
                       const float* __restrict__ dinv,
                       const int* __restrict__ rowstart,
                       const int* __restrict__ rank,
                       int2* __restrict__ csr, int e_cnt) {
    int e = blockIdx.x * blockDim.x + threadIdx.x;
    if (e >= e_cnt) return;
    int s = src[e], d = dst[e];
    int pos = rowstart[d] + rank[e];
    float w = dinv[s] * dinv[d];
    csr[pos] = make_int2(s, __float_as_int(w));
}

// ---------------- fused per-layer kernel ----------------
// Block = 256 threads (4 waves) = 16 output rows -> 3125 blocks, ~28 waves/CU
// (LDS-limited: 20.6 KB/block -> 7 blocks/CU). Occupancy comes from MORE
// BLOCKS, not fatter blocks.
// SPILL NOTE (rounds 7-8 lesson): 512-thread variants with csr prefetch
// spilled (~370-470 MB/dispatch scratch writes) at both launch_bounds (512,8)
// and (512,4). This kernel is the round-4 spill-free structure simplified:
// one row per 16-lane group, no prefetch pipeline, phase-2 tile = 1 row x 4
// cols per lane. VERIFIED spill-free round 9 (k_layer < 46 us).
// RACE NOTE: xin and out must NOT alias within one dispatch — the gather
// reads arbitrary rows of xin while this block writes its own rows of out.
// kernel_launch ping-pongs layer outputs (out / bufA) to guarantee this.
__global__ __launch_bounds__(256) void k_layer(const int* __restrict__ rowstart,
                                               const int* __restrict__ deg,
                                               const float* __restrict__ dinv,
                                               const int2* __restrict__ csr,
                                               const float* __restrict__ xin,
                                               const float* __restrict__ W,
                                               const float* __restrict__ b,
                                               const float* __restrict__ gamma,
                                               const float* __restrict__ beta,
                                               float* __restrict__ out, int n) {
    __shared__ float ws[DIM * DIM];
    __shared__ float xs[RPB * XS_STRIDE];
    int t = threadIdx.x;
    int base = blockIdx.x * RPB;

    {   // stage W: 1024 float4 across 256 threads; issued first so the loads
        // overlap aggregation latency.
        const float4* W4 = (const float4*)W;
        float4* ws4 = (float4*)ws;
#pragma unroll
        for (int i = 0; i < 4; i++) ws4[t + 256 * i] = W4[t + 256 * i];
    }

    // ---- phase 1: aggregation into xs ----
    int wave = t >> 6, lane = t & 63;
    int rs = lane >> 4;    // row slot 0..3
    int fq = lane & 15;    // feature quad 0..15 (float4 each)
    int lrow = wave * 4 + rs;          // local row 0..15
    int row = base + lrow;
    const float4* xin4 = (const float4*)xin;

    float4 acc = make_float4(0.f, 0.f, 0.f, 0.f);
    if (row < n) {
        int s0 = rowstart[row];
        int cnt = deg[row];
        int i = 0;
        for (; i + 4 <= cnt; i += 4) {
            int2 e0 = csr[s0 + i + 0];
            int2 e1 = csr[s0 + i + 1];
            int2 e2 = csr[s0 + i + 2];
            int2 e3 = csr[s0 + i + 3];
            float4 h0 = xin4[(size_t)e0.x * 16 + fq];
            float4 h1 = xin4[(size_t)e1.x * 16 + fq];
            float4 h2 = xin4[(size_t)e2.x * 16 + fq];
            float4 h3 = xin4[(size_t)e3.x * 16 + fq];
            float w0 = __int_as_float(e0.y);
            float w1 = __int_as_float(e1.y);
            float w2 = __int_as_float(e2.y);
            float w3 = __int_as_float(e3.y);
            acc.x = fmaf(w0, h0.x, acc.x);
            acc.y = fmaf(w0, h0.y, acc.y);
            acc.z = fmaf(w0, h0.z, acc.z);
            acc.w = fmaf(w0, h0.w, acc.w);
            acc.x = fmaf(w1, h1.x, acc.x);
            acc.y = fmaf(w1, h1.y, acc.y);
            acc.z = fmaf(w1, h1.z, acc.z);
            acc.w = fmaf(w1, h1.w, acc.w);
            acc.x = fmaf(w2, h2.x, acc.x);
            acc.y = fmaf(w2, h2.y, acc.y);
            acc.z = fmaf(w2, h2.z, acc.z);
            acc.w = fmaf(w2, h2.w, acc.w);
            acc.x = fmaf(w3, h3.x, acc.x);
            acc.y = fmaf(w3, h3.y, acc.y);
            acc.z = fmaf(w3, h3.z, acc.z);
            acc.w = fmaf(w3, h3.w, acc.w);
        }
        for (; i < cnt; i++) {
            int2 e0 = csr[s0 + i];
            float4 h0 = xin4[(size_t)e0.x * 16 + fq];
            float w0 = __int_as_float(e0.y);
            acc.x = fmaf(w0, h0.x, acc.x);
            acc.y = fmaf(w0, h0.y, acc.y);
            acc.z = fmaf(w0, h0.z, acc.z);
            acc.w = fmaf(w0, h0.w, acc.w);
        }
        // self-loop: dinv^2 * x[row]
        float di = dinv[row];
        float w = di * di;
        float4 xv = xin4[(size_t)row * 16 + fq];
        acc.x = fmaf(w, xv.x, acc.x);
        acc.y = fmaf(w, xv.y, acc.y);
        acc.z = fmaf(w, xv.z, acc.z);
        acc.w = fmaf(w, xv.w, acc.w);
    }
    *(float4*)(xs + lrow * XS_STRIDE + fq * 4) = acc;
    __syncthreads();

    // ---- phase 2: GEMM + bias + LN + relu ----
    // Each lane: out[row][fq*4 .. fq*4+3] = sum_k xs[lrow][k] * W[k][fq*4..].
    // xs reads are group-broadcast (free); ws reads are float4-coalesced.
    float4 a2 = make_float4(0.f, 0.f, 0.f, 0.f);
    for (int kc = 0; kc < 16; kc++) {
        float4 xv = *(const float4*)(xs + lrow * XS_STRIDE + kc * 4);
        float4 w0 = *(const float4*)(ws + (4 * kc + 0) * DIM + fq * 4);
        float4 w1 = *(const float4*)(ws + (4 * kc + 1) * DIM + fq * 4);
        float4 w2 = *(const float4*)(ws + (4 * kc + 2) * DIM + fq * 4);
        float4 w3 = *(const float4*)(ws + (4 * kc + 3) * DIM + fq * 4);
        a2.x = fmaf(xv.x, w0.x, a2.x);
        a2.y = fmaf(xv.x, w0.y, a2.y);
        a2.z = fmaf(xv.x, w0.z, a2.z);
        a2.w = fmaf(xv.x, w0.w, a2.w);
        a2.x = fmaf(xv.y, w1.x, a2.x);
        a2.y = fmaf(xv.y, w1.y, a2.y);
        a2.z = fmaf(xv.y, w1.z, a2.z);
        a2.w = fmaf(xv.y, w1.w, a2.w);
        a2.x = fmaf(xv.z, w2.x, a2.x);
        a2.y = fmaf(xv.z, w2.y, a2.y);
        a2.z = fmaf(xv.z, w2.z, a2.z);
        a2.w = fmaf(xv.z, w2.w, a2.w);
        a2.x = fmaf(xv.w, w3.x, a2.x);
        a2.y = fmaf(xv.w, w3.y, a2.y);
        a2.z = fmaf(xv.w, w3.z, a2.z);
        a2.w = fmaf(xv.w, w3.w, a2.w);
    }

    float4 b4 = *(const float4*)(b + fq * 4);
    float4 g4 = *(const float4*)(gamma + fq * 4);
    float4 be4 = *(const float4*)(beta + fq * 4);

    float4 v = make_float4(a2.x + b4.x, a2.y + b4.y, a2.z + b4.z, a2.w + b4.w);
    float s = v.x + v.y + v.z + v.w;
    s += __shfl_xor(s, 1, 64);
    s += __shfl_xor(s, 2, 64);
    s += __shfl_xor(s, 4, 64);
    s += __shfl_xor(s, 8, 64);
    float mu = s * (1.0f / 64.0f);
    float4 d = make_float4(v.x - mu, v.y - mu, v.z - mu, v.w - mu);
    float q = d.x * d.x + d.y * d.y + d.z * d.z + d.w * d.w;
    q += __shfl_xor(q, 1, 64);
    q += __shfl_xor(q, 2, 64);
    q += __shfl_xor(q, 4, 64);
    q += __shfl_xor(q, 8, 64);
    float rstd = rsqrtf(q * (1.0f / 64.0f) + LN_EPS);
    float4 y = make_float4(fmaxf(fmaf(d.x * rstd, g4.x, be4.x), 0.f),
                           fmaxf(fmaf(d.y * rstd, g4.y, be4.y), 0.f),
                           fmaxf(fmaf(d.z * rstd, g4.z, be4.z), 0.f),
                           fmaxf(fmaf(d.w * rstd, g4.w, be4.w), 0.f));
    if (row < n)
        *(float4*)(out + (size_t)row * DIM + fq * 4) = y;
}

// ---------------- launch ----------------

extern "C" void kernel_launch(void* const* d_in, const int* in_sizes, int n_in,
                              void* d_out, int out_size, void* d_ws, size_t ws_size,
                              hipStream_t stream) {
    const float* x      = (const float*)d_in[0];
    const int*   ei     = (const int*)  d_in[1];
    const float* Ws     = (const float*)d_in[2];
    const float* bs     = (const float*)d_in[3];
    const float* gammas = (const float*)d_in[4];
    const float* betas  = (const float*)d_in[5];
    float* out = (float*)d_out;

    int n = in_sizes[0] / DIM;
    int E = in_sizes[1] / 2;
    int n_layers = in_sizes[2] / (DIM * DIM);

    const int* srcp = ei;
    const int* dstp = ei + E;

    // ws layout (ints): deg[n] | rowstart[n] | dinv[n] | counter[2] |
    //                   rank[E] | csr[E] int2 | bufA[n*64] float
    // csr offset = (3n + 2 + E) ints = 150002 + 800000 = 950002 ints
    //            = 3800008 bytes, 8B-aligned for int2. (n=50000, E=800000)
    int* deg      = (int*)d_ws;
    int* rowstart = deg + n;
    float* dinv   = (float*)(rowstart + n);
    int* counter  = (int*)(dinv + n);
    int* rank     = counter + 2;
    int2* csr     = (int2*)(rank + E);
    float* bufA   = (float*)(csr + E);

    int nb_n = (n + 255) / 256;
    int nb_e = (E + 255) / 256;

    k_zero   <<<nb_n, 256, 0, stream>>>(deg, counter, n);
    k_count  <<<nb_e, 256, 0, stream>>>(dstp, deg, rank, E);
    k_reserve<<<nb_n, 256, 0, stream>>>(deg, rowstart, dinv, counter, n);
    k_fill   <<<nb_e, 256, 0, stream>>>(srcp, dstp, dinv, rowstart, rank, csr, E);

    // Ping-pong layer outputs so xin never aliases the write target within
    // a dispatch (the gather reads arbitrary rows). Final layer lands in out.
    int nb_tile = (n + RPB - 1) / RPB;
    const float* src_buf = x;
    for (int i = 0; i < n_layers; i++) {
        float* dst = (((n_layers - 1 - i) & 1) == 0) ? out : bufA;
        k_layer<<<nb_tile, 256, 0, stream>>>(rowstart, deg, dinv, csr, src_buf,
                                             Ws + (size_t)i * DIM * DIM,
                                             bs + (size_t)i * DIM,
                                             gammas + (size_t)i * DIM,
                                             betas + (size_t)i * DIM, dst, n);
        src_buf = dst;
    }
}